// Round 2
// baseline (326.245 us; speedup 1.0000x reference)
//
#include <hip/hip_runtime.h>

// Problem constants
#define NTOK   32768
#define CDIM   128
#define NH     8
#define QT     32     // rows per k_out block

typedef __bf16 bf16;
typedef __bf16 bf16x4v __attribute__((ext_vector_type(4)));
typedef __bf16 bf16x8v __attribute__((ext_vector_type(8)));
typedef float  f32x4   __attribute__((ext_vector_type(4)));

__device__ __forceinline__ f32x4 mfma16(bf16x8v a, bf16x8v b, f32x4 c) {
  return __builtin_amdgcn_mfma_f32_16x16x32_bf16(a, b, c, 0, 0, 0);
}

__device__ __forceinline__ float xred16(float v) {
  v += __shfl_xor(v, 1);
  v += __shfl_xor(v, 2);
  v += __shfl_xor(v, 4);
  v += __shfl_xor(v, 8);
  return v;
}

// swizzled element index for row-major [R][128] bf16 LDS tiles:
// byte ^= ((row&7)<<4)  ==  elem ^= ((row&7)<<3)
__device__ __forceinline__ int sidx(int row, int col) {
  return row * 128 + (col ^ ((row & 7) << 3));
}

// ---------------------------------------------------------------------------
// k_prep: wq/wk/wv -> bf16; (h==0) rows of Wvs = sum_h Wv; Wvbs = sum_h Wv_b
// grid 1024 (h,o) x 128 threads
// ---------------------------------------------------------------------------
__global__ void __launch_bounds__(128) k_prep(
    const float* __restrict__ Wq, const float* __restrict__ Wk,
    const float* __restrict__ Wv, const float* __restrict__ Wv_b,
    bf16* __restrict__ wq, bf16* __restrict__ wk, bf16* __restrict__ wv,
    float* __restrict__ Wvs, float* __restrict__ Wvbs)
{
  const int h = blockIdx.x >> 7, o = blockIdx.x & 127;
  const int i = threadIdx.x;
  const int base = (h * CDIM + o) * CDIM;
  wq[base + i] = (bf16)Wq[base + i];
  wk[base + i] = (bf16)Wk[base + i];
  wv[base + i] = (bf16)Wv[base + i];
  if (h == 0) {
    float s = 0.f;
#pragma unroll
    for (int hh = 0; hh < NH; ++hh) s += Wv[(hh * CDIM + o) * CDIM + i];
    Wvs[o * CDIM + i] = s;
    if (o == 0) {
      float sb = 0.f;
#pragma unroll
      for (int hh = 0; hh < NH; ++hh) sb += Wv_b[hh * CDIM + i];
      Wvbs[i] = sb;
    }
  }
}

// ---------------------------------------------------------------------------
// k_prep2: W2s[o][i] = sum_d vmw[o][d]*Wvs[d][i] (bf16); b2s[o] = vmw[o].Wvbs + 8*vmb[o]
// grid 128 (o) x 128 threads (i)
// ---------------------------------------------------------------------------
__global__ void __launch_bounds__(128) k_prep2(
    const float* __restrict__ vmw, const float* __restrict__ vmb,
    const float* __restrict__ Wvs, const float* __restrict__ Wvbs,
    bf16* __restrict__ w2s, float* __restrict__ b2s)
{
  const int o = blockIdx.x, i = threadIdx.x;
  __shared__ float s_vm[128];
  __shared__ float s_rd[128];
  s_vm[i] = vmw[o * CDIM + i];
  __syncthreads();
  float acc = 0.f;
  for (int d = 0; d < CDIM; ++d) acc = fmaf(s_vm[d], Wvs[d * CDIM + i], acc);
  w2s[o * CDIM + i] = (bf16)acc;
  s_rd[i] = s_vm[i] * Wvbs[i];
  __syncthreads();
  for (int st = 64; st > 0; st >>= 1) {
    if (i < st) s_rd[i] += s_rd[i + st];
    __syncthreads();
  }
  if (i == 0) b2s[o] = s_rd[0] + 8.f * vmb[o];
}

// ---------------------------------------------------------------------------
// k_ktv: per (chunk c, head h): ks/v GEMMs, phi(ks), partial ktv + ksum.
// grid nchunk*8, 256 threads (4 waves), nsub 64-row subtiles per chunk
// ---------------------------------------------------------------------------
__global__ void __launch_bounds__(256, 3) k_ktv(
    const float* __restrict__ src,
    const bf16* __restrict__ wk, const bf16* __restrict__ wv,
    const float* __restrict__ Wk_b, const float* __restrict__ Wv_b,
    const float* __restrict__ nscale,
    bf16* __restrict__ ktv_part, float* __restrict__ ksum_part, int nsub)
{
  const int bid = blockIdx.x;
  const int h = bid & 7, c = bid >> 3;
  const int tid = threadIdx.x;
  const int w = tid >> 6, l = tid & 63;
  const int l15 = l & 15, lg = l >> 4;
  const int os = w * 32;

  __shared__ bf16 s_src[64 * 128];         // XOR-swizzled [n][i]
  __shared__ bf16 s_phiT[128][68];         // [m][n] (+pad, 8B-aligned rows)
  __shared__ bf16 s_vT[128][68];           // [d][n]
  __shared__ float s_red[4][64][2] __attribute__((aligned(16)));
  __shared__ float s_scale[64] __attribute__((aligned(16)));

  const float inv_ds = 1.f / (fabsf(nscale[0]) + 1e-6f);
  const f32x4 z4 = {0.f, 0.f, 0.f, 0.f};

  float bK[2], bV[2];
#pragma unroll
  for (int ot = 0; ot < 2; ++ot) {
    bK[ot] = Wk_b[h * CDIM + os + ot * 16 + l15];
    bV[ot] = Wv_b[h * CDIM + os + ot * 16 + l15];
  }

  const int wd = (w >> 1) * 64, wm = (w & 1) * 64;
  f32x4 acc[4][4];
#pragma unroll
  for (int dt = 0; dt < 4; ++dt)
#pragma unroll
    for (int mt = 0; mt < 4; ++mt) acc[dt][mt] = z4;
  float ksacc[2] = {0.f, 0.f};

  const int base_row = c * (nsub * 64);

  // prologue: stage subtile 0
#pragma unroll
  for (int j = 0; j < 8; ++j) {
    const int flat = tid + j * 256;
    const int n = flat >> 5, c4 = (flat & 31) * 4;
    f32x4 v = *(const f32x4*)(src + (base_row + n) * CDIM + c4);
    bf16x4v bv;
    bv[0] = (bf16)v[0]; bv[1] = (bf16)v[1]; bv[2] = (bf16)v[2]; bv[3] = (bf16)v[3];
    *(bf16x4v*)&s_src[sidx(n, c4)] = bv;
  }
  __syncthreads();

  for (int s = 0; s < nsub; ++s) {
    // ks/v GEMMs (M=n, N=o strip, K=i)
    f32x4 accK[4][2], accV[4][2];
#pragma unroll
    for (int nt = 0; nt < 4; ++nt)
#pragma unroll
      for (int ot = 0; ot < 2; ++ot) { accK[nt][ot] = z4; accV[nt][ot] = z4; }
#pragma unroll
    for (int kk = 0; kk < 4; ++kk) {
      bf16x8v a[4];
#pragma unroll
      for (int nt = 0; nt < 4; ++nt)
        a[nt] = *(const bf16x8v*)&s_src[sidx(nt * 16 + l15, kk * 32 + lg * 8)];
#pragma unroll
      for (int ot = 0; ot < 2; ++ot) {
        const int wo = (h * CDIM + os + ot * 16 + l15) * CDIM + kk * 32 + lg * 8;
        bf16x8v wkf = *(const bf16x8v*)(wk + wo);
        bf16x8v wvf = *(const bf16x8v*)(wv + wo);
#pragma unroll
        for (int nt = 0; nt < 4; ++nt) {
          accK[nt][ot] = mfma16(a[nt], wkf, accK[nt][ot]);
          accV[nt][ot] = mfma16(a[nt], wvf, accV[nt][ot]);
        }
      }
    }
    // x^2 + strip norms
#pragma unroll
    for (int nt = 0; nt < 4; ++nt)
#pragma unroll
      for (int r = 0; r < 4; ++r) {
        float a2 = 0.f, a4 = 0.f;
#pragma unroll
        for (int ot = 0; ot < 2; ++ot) {
          float x = (fmaxf(accK[nt][ot][r] + bK[ot], 0.f) + 1e-6f) * inv_ds;
          float x2 = x * x;
          accK[nt][ot][r] = x2;
          a2 += x2;
          a4 += x2 * x2;
        }
        a2 = xred16(a2);
        a4 = xred16(a4);
        if (l15 == 0) {
          s_red[w][nt * 16 + lg * 4 + r][0] = a2;
          s_red[w][nt * 16 + lg * 4 + r][1] = a4;
        }
      }
    __syncthreads();  // B1
    if (tid < 64) {
      float S2 = s_red[0][tid][0] + s_red[1][tid][0] + s_red[2][tid][0] + s_red[3][tid][0];
      float S4 = s_red[0][tid][1] + s_red[1][tid][1] + s_red[2][tid][1] + s_red[3][tid][1];
      s_scale[tid] = sqrtf(S2) / (sqrtf(S4) + 1e-8f);
    }
    __syncthreads();  // B2
    // transposed writes: phi = x2*scale -> s_phiT[m][n], v+bias -> s_vT[d][n]
#pragma unroll
    for (int nt = 0; nt < 4; ++nt) {
      f32x4 sc = *(const f32x4*)&s_scale[nt * 16 + lg * 4];
#pragma unroll
      for (int ot = 0; ot < 2; ++ot) {
        bf16x4v ph, vv;
#pragma unroll
        for (int r = 0; r < 4; ++r) {
          float p = accK[nt][ot][r] * sc[r];
          ksacc[ot] += p;
          ph[r] = (bf16)p;
          vv[r] = (bf16)(accV[nt][ot][r] + bV[ot]);
        }
        const int colb = os + ot * 16 + l15;
        *(bf16x4v*)&s_phiT[colb][nt * 16 + lg * 4] = ph;
        *(bf16x4v*)&s_vT[colb][nt * 16 + lg * 4] = vv;
      }
    }
    __syncthreads();  // B3
    // stage next subtile (overlaps ktv MFMA)
    if (s + 1 < nsub) {
      const int nb = base_row + (s + 1) * 64;
#pragma unroll
      for (int j = 0; j < 8; ++j) {
        const int flat = tid + j * 256;
        const int n = flat >> 5, c4 = (flat & 31) * 4;
        f32x4 v = *(const f32x4*)(src + (nb + n) * CDIM + c4);
        bf16x4v bv;
        bv[0] = (bf16)v[0]; bv[1] = (bf16)v[1]; bv[2] = (bf16)v[2]; bv[3] = (bf16)v[3];
        *(bf16x4v*)&s_src[sidx(n, c4)] = bv;
      }
    }
    // ktv += v^T phi
#pragma unroll
    for (int kk = 0; kk < 2; ++kk) {
      bf16x8v aV[4], bP[4];
#pragma unroll
      for (int dt = 0; dt < 4; ++dt)
        aV[dt] = *(const bf16x8v*)&s_vT[wd + dt * 16 + l15][kk * 32 + lg * 8];
#pragma unroll
      for (int mt = 0; mt < 4; ++mt)
        bP[mt] = *(const bf16x8v*)&s_phiT[wm + mt * 16 + l15][kk * 32 + lg * 8];
#pragma unroll
      for (int dt = 0; dt < 4; ++dt)
#pragma unroll
        for (int mt = 0; mt < 4; ++mt)
          acc[dt][mt] = mfma16(aV[dt], bP[mt], acc[dt][mt]);
    }
    if (s + 1 < nsub) __syncthreads();  // B4: stage complete
  }

  // ksum partial
#pragma unroll
  for (int ot = 0; ot < 2; ++ot) {
    ksacc[ot] += __shfl_xor(ksacc[ot], 16);
    ksacc[ot] += __shfl_xor(ksacc[ot], 32);
  }
  if (l < 16) {
#pragma unroll
    for (int ot = 0; ot < 2; ++ot)
      ksum_part[(c * NH + h) * CDIM + os + ot * 16 + l] = ksacc[ot];
  }
  // ktv partial store
  bf16* kp = ktv_part + (c * NH + h) * CDIM * CDIM;
#pragma unroll
  for (int dt = 0; dt < 4; ++dt)
#pragma unroll
    for (int mt = 0; mt < 4; ++mt)
#pragma unroll
      for (int r = 0; r < 4; ++r)
        kp[(wd + dt * 16 + lg * 4 + r) * CDIM + wm + mt * 16 + l15] = (bf16)acc[dt][mt][r];
}

// ---------------------------------------------------------------------------
// k_finish: ktvaug[h][144][128] bf16: rows 0..127 = sum of ktv partials,
//           row 128 = ksum, rows 129..143 = 0.  grid 576 x 256
// ---------------------------------------------------------------------------
__global__ void __launch_bounds__(256) k_finish(
    const bf16* __restrict__ ktv_part, const float* __restrict__ ksum_part,
    bf16* __restrict__ ktvaug, int nchunk)
{
  const int t = blockIdx.x * 256 + threadIdx.x;   // < 8*144*128
  const int h = t / (144 * 128);
  const int rem = t - h * 144 * 128;
  const int d = rem >> 7, m = rem & 127;
  float a = 0.f;
  if (d < 128) {
    for (int c = 0; c < nchunk; ++c) a += (float)ktv_part[(c * NH + h) * 16384 + (d << 7) + m];
  } else if (d == 128) {
    for (int c = 0; c < nchunk; ++c) a += ksum_part[(c * NH + h) * CDIM + m];
  }
  ktvaug[t] = (bf16)a;
}

// ---------------------------------------------------------------------------
// k_out: per 32-row tile. Per head: qs GEMM -> x2 -> (dbuf LDS) ->
//        num GEMM vs ktvaug (aug row gives denominator T), accO += num/T.
//        Then one fused vss GEMM (W2s/b2s), mean, time coord.
// grid 1024 x 256, 1 barrier per head.
// ---------------------------------------------------------------------------
__global__ void __launch_bounds__(256, 4) k_out(
    const float* __restrict__ query, const float* __restrict__ src,
    const bf16* __restrict__ wq, const float* __restrict__ Wq_b,
    const bf16* __restrict__ ktvaug,
    const bf16* __restrict__ w2s, const float* __restrict__ b2s,
    float* __restrict__ out)
{
  const int nb = blockIdx.x * QT;
  const int tid = threadIdx.x;
  const int w = tid >> 6, l = tid & 63;
  const int l15 = l & 15, lg = l >> 4;
  const int os = w * 32;

  __shared__ bf16 s_q[QT * 128];      // XOR-swizzled
  __shared__ bf16 s_s[QT * 128];
  __shared__ bf16 s_phi[2][QT * 128]; // double-buffered x2 tile
  __shared__ float s_time[4][QT] __attribute__((aligned(16)));

  const f32x4 z4 = {0.f, 0.f, 0.f, 0.f};

  // stage query + source (f32 -> bf16, swizzled)
#pragma unroll
  for (int j = 0; j < 4; ++j) {
    const int flat = tid + j * 256;
    const int n = flat >> 5, c4 = (flat & 31) * 4;
    f32x4 vq = *(const f32x4*)(query + (nb + n) * CDIM + c4);
    f32x4 vs = *(const f32x4*)(src + (nb + n) * CDIM + c4);
    bf16x4v bq, bs;
    bq[0] = (bf16)vq[0]; bq[1] = (bf16)vq[1]; bq[2] = (bf16)vq[2]; bq[3] = (bf16)vq[3];
    bs[0] = (bf16)vs[0]; bs[1] = (bf16)vs[1]; bs[2] = (bf16)vs[2]; bs[3] = (bf16)vs[3];
    *(bf16x4v*)&s_q[sidx(n, c4)] = bq;
    *(bf16x4v*)&s_s[sidx(n, c4)] = bs;
  }

  f32x4 accO[2][2];
#pragma unroll
  for (int nt = 0; nt < 2; ++nt)
#pragma unroll
    for (int ot = 0; ot < 2; ++ot) accO[nt][ot] = z4;

  __syncthreads();

  for (int h = 0; h < NH; ++h) {
    // qs GEMM
    f32x4 accQ[2][2];
#pragma unroll
    for (int nt = 0; nt < 2; ++nt)
#pragma unroll
      for (int ot = 0; ot < 2; ++ot) accQ[nt][ot] = z4;
#pragma unroll
    for (int kk = 0; kk < 4; ++kk) {
      bf16x8v a[2];
#pragma unroll
      for (int nt = 0; nt < 2; ++nt)
        a[nt] = *(const bf16x8v*)&s_q[sidx(nt * 16 + l15, kk * 32 + lg * 8)];
#pragma unroll
      for (int ot = 0; ot < 2; ++ot) {
        bf16x8v bw = *(const bf16x8v*)(wq + (h * CDIM + os + ot * 16 + l15) * CDIM + kk * 32 + lg * 8);
#pragma unroll
        for (int nt = 0; nt < 2; ++nt)
          accQ[nt][ot] = mfma16(a[nt], bw, accQ[nt][ot]);
      }
    }
    float bQ[2];
#pragma unroll
    for (int ot = 0; ot < 2; ++ot) bQ[ot] = Wq_b[h * CDIM + os + ot * 16 + l15];

    // x2 (raw, scale-free) -> s_phi[h&1]
    bf16* ph = s_phi[h & 1];
#pragma unroll
    for (int nt = 0; nt < 2; ++nt)
#pragma unroll
      for (int ot = 0; ot < 2; ++ot)
#pragma unroll
        for (int r = 0; r < 4; ++r) {
          float x = fmaxf(accQ[nt][ot][r] + bQ[ot], 0.f) + 1e-6f;
          const int row = nt * 16 + lg * 4 + r;
          ph[sidx(row, os + ot * 16 + l15)] = (bf16)(x * x);
        }
    __syncthreads();  // B1 (only barrier in the head loop)

    // numerator GEMM + denominator via aug row (d=128 of ktvaug = ksum)
    const bf16* kb = ktvaug + h * (144 * 128);
    f32x4 accN[2][2], accT[2];
#pragma unroll
    for (int nt = 0; nt < 2; ++nt) {
      accT[nt] = z4;
#pragma unroll
      for (int dt = 0; dt < 2; ++dt) accN[nt][dt] = z4;
    }
#pragma unroll
    for (int kk = 0; kk < 4; ++kk) {
      bf16x8v a[2];
#pragma unroll
      for (int nt = 0; nt < 2; ++nt)
        a[nt] = *(const bf16x8v*)&ph[sidx(nt * 16 + l15, kk * 32 + lg * 8)];
#pragma unroll
      for (int dt = 0; dt < 2; ++dt) {
        bf16x8v bk = *(const bf16x8v*)(kb + (os + dt * 16 + l15) * CDIM + kk * 32 + lg * 8);
#pragma unroll
        for (int nt = 0; nt < 2; ++nt)
          accN[nt][dt] = mfma16(a[nt], bk, accN[nt][dt]);
      }
      bf16x8v bt = *(const bf16x8v*)(kb + (128 + l15) * CDIM + kk * 32 + lg * 8);
#pragma unroll
      for (int nt = 0; nt < 2; ++nt)
        accT[nt] = mfma16(a[nt], bt, accT[nt]);
    }
    // accO += accN / T   (T broadcast from l15==0 lane of each 16-group)
#pragma unroll
    for (int nt = 0; nt < 2; ++nt)
#pragma unroll
      for (int r = 0; r < 4; ++r) {
        float tr = __shfl(accT[nt][r], l & 48);
        float m = 1.0f / tr;
#pragma unroll
        for (int dt = 0; dt < 2; ++dt)
          accO[nt][dt][r] = fmaf(accN[nt][dt][r], m, accO[nt][dt][r]);
      }
  }

  // fused vss GEMM (accumulates straight into accO)
#pragma unroll
  for (int kk = 0; kk < 4; ++kk) {
    bf16x8v a[2];
#pragma unroll
    for (int nt = 0; nt < 2; ++nt)
      a[nt] = *(const bf16x8v*)&s_s[sidx(nt * 16 + l15, kk * 32 + lg * 8)];
#pragma unroll
    for (int ot = 0; ot < 2; ++ot) {
      bf16x8v bw = *(const bf16x8v*)(w2s + (os + ot * 16 + l15) * CDIM + kk * 32 + lg * 8);
#pragma unroll
      for (int nt = 0; nt < 2; ++nt)
        accO[nt][ot] = mfma16(a[nt], bw, accO[nt][ot]);
    }
  }
  float bb[2];
#pragma unroll
  for (int ot = 0; ot < 2; ++ot) bb[ot] = b2s[os + ot * 16 + l15];

  // mean + time coordinate
  float ps[2][4];
#pragma unroll
  for (int nt = 0; nt < 2; ++nt)
#pragma unroll
    for (int r = 0; r < 4; ++r) ps[nt][r] = 0.f;
#pragma unroll
  for (int nt = 0; nt < 2; ++nt)
#pragma unroll
    for (int ot = 0; ot < 2; ++ot)
#pragma unroll
      for (int r = 0; r < 4; ++r) {
        float v = (accO[nt][ot][r] + bb[ot]) * 0.125f;
        accO[nt][ot][r] = v;
        ps[nt][r] += v * v;
      }
#pragma unroll
  for (int nt = 0; nt < 2; ++nt)
#pragma unroll
    for (int r = 0; r < 4; ++r) {
      float t = xred16(ps[nt][r]);
      if (l15 == 0) s_time[w][nt * 16 + lg * 4 + r] = t;
    }
#pragma unroll
  for (int nt = 0; nt < 2; ++nt)
#pragma unroll
    for (int ot = 0; ot < 2; ++ot)
#pragma unroll
      for (int r = 0; r < 4; ++r)
        out[(nb + nt * 16 + lg * 4 + r) * 129 + 1 + os + ot * 16 + l15] = accO[nt][ot][r];
  __syncthreads();
  if (tid < QT) {
    float S = 1.0f + s_time[0][tid] + s_time[1][tid] + s_time[2][tid] + s_time[3][tid];
    out[(nb + tid) * 129] = sqrtf(S);
  }
}

// ---------------------------------------------------------------------------
extern "C" void kernel_launch(void* const* d_in, const int* in_sizes, int n_in,
                              void* d_out, int out_size, void* d_ws, size_t ws_size,
                              hipStream_t stream) {
  const float* query  = (const float*)d_in[0];
  const float* source = (const float*)d_in[1];
  const float* Wq_w   = (const float*)d_in[2];
  const float* Wq_b   = (const float*)d_in[3];
  const float* Wk_w   = (const float*)d_in[4];
  const float* Wk_b   = (const float*)d_in[5];
  const float* Wv_w   = (const float*)d_in[6];
  const float* Wv_b   = (const float*)d_in[7];
  const float* vmw    = (const float*)d_in[8];
  const float* vmb    = (const float*)d_in[9];
  const float* ns     = (const float*)d_in[10];

  char* ws = (char*)d_ws;
  bf16*  wq        = (bf16*)(ws + 0);          // 262144
  bf16*  wk        = (bf16*)(ws + 262144);     // 262144
  bf16*  wv        = (bf16*)(ws + 524288);     // 262144
  bf16*  w2s       = (bf16*)(ws + 786432);     // 32768
  float* b2s       = (float*)(ws + 819200);    // 512
  float* Wvs       = (float*)(ws + 819712);    // 65536
  float* Wvbs      = (float*)(ws + 885248);    // 512
  bf16*  ktvaug    = (bf16*)(ws + 885760);     // 294912 (8*144*128*2)
  float* ksum_part = (float*)(ws + 1180672);   // up to 524288
  bf16*  ktv_part  = (bf16*)(ws + 1704960);    // nchunk*8*16384*2

  // nchunk=128 needs ~35.3 MB of ws; fall back to 64 otherwise.
  const size_t need128 = 1704960ull + 128ull * NH * 16384ull * 2ull;
  const int nchunk = (ws_size >= need128) ? 128 : 64;
  const int nsub = (NTOK / nchunk) / 64;

  k_prep<<<1024, 128, 0, stream>>>(Wq_w, Wk_w, Wv_w, Wv_b, wq, wk, wv, Wvs, Wvbs);
  k_prep2<<<128, 128, 0, stream>>>(vmw, vmb, Wvs, Wvbs, w2s, b2s);
  k_ktv<<<nchunk * NH, 256, 0, stream>>>(source, wk, wv, Wk_b, Wv_b, ns, ktv_part, ksum_part, nsub);
  k_finish<<<576, 256, 0, stream>>>(ktv_part, ksum_part, ktvaug, nchunk);
  k_out<<<NTOK / QT, 256, 0, stream>>>(query, source, wq, Wq_b, ktvaug, w2s, b2s, (float*)d_out);
}

// Round 3
// 178.308 us; speedup vs baseline: 1.8297x; 1.8297x over previous
//
#include <hip/hip_runtime.h>

// Problem constants
#define NTOK   32768
#define CDIM   128
#define NH     8
#define QT     32     // rows per k_out block
#define NCHUNK 64     // split-K chunks for ktv
#define NSUB   8      // 64-row subtiles per chunk (NCHUNK*NSUB*64 == NTOK)

typedef __bf16 bf16;
typedef __bf16 bf16x4v __attribute__((ext_vector_type(4)));
typedef __bf16 bf16x8v __attribute__((ext_vector_type(8)));
typedef float  f32x4   __attribute__((ext_vector_type(4)));

__device__ __forceinline__ f32x4 mfma16(bf16x8v a, bf16x8v b, f32x4 c) {
  return __builtin_amdgcn_mfma_f32_16x16x32_bf16(a, b, c, 0, 0, 0);
}

__device__ __forceinline__ float xred16(float v) {
  v += __shfl_xor(v, 1);
  v += __shfl_xor(v, 2);
  v += __shfl_xor(v, 4);
  v += __shfl_xor(v, 8);
  return v;
}

// swizzled element index for row-major [R][128] bf16 LDS tiles:
// byte ^= ((row&7)<<4)  ==  elem ^= ((row&7)<<3)
__device__ __forceinline__ int sidx(int row, int col) {
  return row * 128 + (col ^ ((row & 7) << 3));
}

// ---------------------------------------------------------------------------
// k_prep: wq/wk/wv -> bf16; (h==0) rows of Wvs = sum_h Wv; Wvbs = sum_h Wv_b
// ---------------------------------------------------------------------------
__global__ void __launch_bounds__(128) k_prep(
    const float* __restrict__ Wq, const float* __restrict__ Wk,
    const float* __restrict__ Wv, const float* __restrict__ Wv_b,
    bf16* __restrict__ wq, bf16* __restrict__ wk, bf16* __restrict__ wv,
    float* __restrict__ Wvs, float* __restrict__ Wvbs)
{
  const int h = blockIdx.x >> 7, o = blockIdx.x & 127;
  const int i = threadIdx.x;
  const int base = (h * CDIM + o) * CDIM;
  wq[base + i] = (bf16)Wq[base + i];
  wk[base + i] = (bf16)Wk[base + i];
  wv[base + i] = (bf16)Wv[base + i];
  if (h == 0) {
    float s = 0.f;
#pragma unroll
    for (int hh = 0; hh < NH; ++hh) s += Wv[(hh * CDIM + o) * CDIM + i];
    Wvs[o * CDIM + i] = s;
    if (o == 0) {
      float sb = 0.f;
#pragma unroll
      for (int hh = 0; hh < NH; ++hh) sb += Wv_b[hh * CDIM + i];
      Wvbs[i] = sb;
    }
  }
}

// ---------------------------------------------------------------------------
// k_prep2: W2s[o][i] = sum_d vmw[o][d]*Wvs[d][i] (bf16); b2s[o] = vmw[o].Wvbs + 8*vmb[o]
// ---------------------------------------------------------------------------
__global__ void __launch_bounds__(128) k_prep2(
    const float* __restrict__ vmw, const float* __restrict__ vmb,
    const float* __restrict__ Wvs, const float* __restrict__ Wvbs,
    bf16* __restrict__ w2s, float* __restrict__ b2s)
{
  const int o = blockIdx.x, i = threadIdx.x;
  __shared__ float s_vm[128];
  __shared__ float s_rd[128];
  s_vm[i] = vmw[o * CDIM + i];
  __syncthreads();
  float acc = 0.f;
  for (int d = 0; d < CDIM; ++d) acc = fmaf(s_vm[d], Wvs[d * CDIM + i], acc);
  w2s[o * CDIM + i] = (bf16)acc;
  s_rd[i] = s_vm[i] * Wvbs[i];
  __syncthreads();
  for (int st = 64; st > 0; st >>= 1) {
    if (i < st) s_rd[i] += s_rd[i + st];
    __syncthreads();
  }
  if (i == 0) b2s[o] = s_rd[0] + 8.f * vmb[o];
}

// ---------------------------------------------------------------------------
// k_ktv: per (chunk c, head h): ks/v GEMMs, phi(ks), partial ktv + ksum.
// grid NCHUNK*8 = 512 blocks, 256 threads (4 waves). LDS 53KB -> 2 blocks/CU,
// so __launch_bounds__(256,2): VGPR budget 256, need ~220 -> NO SPILLS.
// ---------------------------------------------------------------------------
__global__ void __launch_bounds__(256, 2) k_ktv(
    const float* __restrict__ src,
    const bf16* __restrict__ wk, const bf16* __restrict__ wv,
    const float* __restrict__ Wk_b, const float* __restrict__ Wv_b,
    const float* __restrict__ nscale,
    bf16* __restrict__ ktv_part, float* __restrict__ ksum_part)
{
  const int bid = blockIdx.x;
  const int h = bid & 7, c = bid >> 3;
  const int tid = threadIdx.x;
  const int w = tid >> 6, l = tid & 63;
  const int l15 = l & 15, lg = l >> 4;
  const int os = w * 32;

  __shared__ bf16 s_src[64 * 128];         // XOR-swizzled [n][i]
  __shared__ bf16 s_phiT[128][68];         // [m][n] (+pad)
  __shared__ bf16 s_vT[128][68];           // [d][n]
  __shared__ float s_red[4][64][2] __attribute__((aligned(16)));
  __shared__ float s_scale[64] __attribute__((aligned(16)));

  const float inv_ds = 1.f / (fabsf(nscale[0]) + 1e-6f);
  const f32x4 z4 = {0.f, 0.f, 0.f, 0.f};

  // hoisted loop-invariant weight B-fragments + biases (~64 VGPRs, fits (256,2))
  bf16x8v bWk[2][4], bWv[2][4];
  float bK[2], bV[2];
#pragma unroll
  for (int ot = 0; ot < 2; ++ot) {
    const int o = os + ot * 16 + l15;
    const bf16* pk = wk + (h * CDIM + o) * CDIM + lg * 8;
    const bf16* pv = wv + (h * CDIM + o) * CDIM + lg * 8;
#pragma unroll
    for (int kk = 0; kk < 4; ++kk) {
      bWk[ot][kk] = *(const bf16x8v*)(pk + kk * 32);
      bWv[ot][kk] = *(const bf16x8v*)(pv + kk * 32);
    }
    bK[ot] = Wk_b[h * CDIM + o];
    bV[ot] = Wv_b[h * CDIM + o];
  }

  const int wd = (w >> 1) * 64, wm = (w & 1) * 64;
  f32x4 acc[4][4];
#pragma unroll
  for (int dt = 0; dt < 4; ++dt)
#pragma unroll
    for (int mt = 0; mt < 4; ++mt) acc[dt][mt] = z4;
  float ksacc[2] = {0.f, 0.f};

  const int base_row = c * (NSUB * 64);

  // prologue: stage subtile 0
#pragma unroll
  for (int j = 0; j < 8; ++j) {
    const int flat = tid + j * 256;
    const int n = flat >> 5, c4 = (flat & 31) * 4;
    f32x4 v = *(const f32x4*)(src + (base_row + n) * CDIM + c4);
    bf16x4v bv;
    bv[0] = (bf16)v[0]; bv[1] = (bf16)v[1]; bv[2] = (bf16)v[2]; bv[3] = (bf16)v[3];
    *(bf16x4v*)&s_src[sidx(n, c4)] = bv;
  }
  __syncthreads();

#pragma unroll 1
  for (int s = 0; s < NSUB; ++s) {
    // ks/v GEMMs (M=n, N=o strip, K=i)
    f32x4 accK[4][2], accV[4][2];
#pragma unroll
    for (int nt = 0; nt < 4; ++nt)
#pragma unroll
      for (int ot = 0; ot < 2; ++ot) { accK[nt][ot] = z4; accV[nt][ot] = z4; }
#pragma unroll
    for (int kk = 0; kk < 4; ++kk) {
      bf16x8v a[4];
#pragma unroll
      for (int nt = 0; nt < 4; ++nt)
        a[nt] = *(const bf16x8v*)&s_src[sidx(nt * 16 + l15, kk * 32 + lg * 8)];
#pragma unroll
      for (int nt = 0; nt < 4; ++nt)
#pragma unroll
        for (int ot = 0; ot < 2; ++ot) {
          accK[nt][ot] = mfma16(a[nt], bWk[ot][kk], accK[nt][ot]);
          accV[nt][ot] = mfma16(a[nt], bWv[ot][kk], accV[nt][ot]);
        }
    }
    // x^2 + strip norms
#pragma unroll
    for (int nt = 0; nt < 4; ++nt)
#pragma unroll
      for (int r = 0; r < 4; ++r) {
        float a2 = 0.f, a4 = 0.f;
#pragma unroll
        for (int ot = 0; ot < 2; ++ot) {
          float x = (fmaxf(accK[nt][ot][r] + bK[ot], 0.f) + 1e-6f) * inv_ds;
          float x2 = x * x;
          accK[nt][ot][r] = x2;
          a2 += x2;
          a4 += x2 * x2;
        }
        a2 = xred16(a2);
        a4 = xred16(a4);
        if (l15 == 0) {
          s_red[w][nt * 16 + lg * 4 + r][0] = a2;
          s_red[w][nt * 16 + lg * 4 + r][1] = a4;
        }
      }
    __syncthreads();  // B1
    if (tid < 64) {
      float S2 = s_red[0][tid][0] + s_red[1][tid][0] + s_red[2][tid][0] + s_red[3][tid][0];
      float S4 = s_red[0][tid][1] + s_red[1][tid][1] + s_red[2][tid][1] + s_red[3][tid][1];
      s_scale[tid] = sqrtf(S2) / (sqrtf(S4) + 1e-8f);
    }
    __syncthreads();  // B2
    // transposed writes: phi = x2*scale -> s_phiT[m][n], v+bias -> s_vT[d][n]
#pragma unroll
    for (int nt = 0; nt < 4; ++nt) {
      f32x4 sc = *(const f32x4*)&s_scale[nt * 16 + lg * 4];
#pragma unroll
      for (int ot = 0; ot < 2; ++ot) {
        bf16x4v ph, vv;
#pragma unroll
        for (int r = 0; r < 4; ++r) {
          float p = accK[nt][ot][r] * sc[r];
          ksacc[ot] += p;
          ph[r] = (bf16)p;
          vv[r] = (bf16)(accV[nt][ot][r] + bV[ot]);
        }
        const int colb = os + ot * 16 + l15;
        *(bf16x4v*)&s_phiT[colb][nt * 16 + lg * 4] = ph;
        *(bf16x4v*)&s_vT[colb][nt * 16 + lg * 4] = vv;
      }
    }
    __syncthreads();  // B3
    // stage next subtile (issues global loads; overlaps the ktv MFMA below)
    if (s + 1 < NSUB) {
      const int nb = base_row + (s + 1) * 64;
#pragma unroll
      for (int j = 0; j < 8; ++j) {
        const int flat = tid + j * 256;
        const int n = flat >> 5, c4 = (flat & 31) * 4;
        f32x4 v = *(const f32x4*)(src + (nb + n) * CDIM + c4);
        bf16x4v bv;
        bv[0] = (bf16)v[0]; bv[1] = (bf16)v[1]; bv[2] = (bf16)v[2]; bv[3] = (bf16)v[3];
        *(bf16x4v*)&s_src[sidx(n, c4)] = bv;
      }
    }
    // ktv += v^T phi
#pragma unroll
    for (int kk = 0; kk < 2; ++kk) {
      bf16x8v aV[4], bP[4];
#pragma unroll
      for (int dt = 0; dt < 4; ++dt)
        aV[dt] = *(const bf16x8v*)&s_vT[wd + dt * 16 + l15][kk * 32 + lg * 8];
#pragma unroll
      for (int mt = 0; mt < 4; ++mt)
        bP[mt] = *(const bf16x8v*)&s_phiT[wm + mt * 16 + l15][kk * 32 + lg * 8];
#pragma unroll
      for (int dt = 0; dt < 4; ++dt)
#pragma unroll
        for (int mt = 0; mt < 4; ++mt)
          acc[dt][mt] = mfma16(aV[dt], bP[mt], acc[dt][mt]);
    }
    if (s + 1 < NSUB) __syncthreads();  // B4: stage complete
  }

  // ksum partial
#pragma unroll
  for (int ot = 0; ot < 2; ++ot) {
    ksacc[ot] += __shfl_xor(ksacc[ot], 16);
    ksacc[ot] += __shfl_xor(ksacc[ot], 32);
  }
  if (l < 16) {
#pragma unroll
    for (int ot = 0; ot < 2; ++ot)
      ksum_part[(c * NH + h) * CDIM + os + ot * 16 + l] = ksacc[ot];
  }
  // ktv partial store
  bf16* kp = ktv_part + (c * NH + h) * CDIM * CDIM;
#pragma unroll
  for (int dt = 0; dt < 4; ++dt)
#pragma unroll
    for (int mt = 0; mt < 4; ++mt)
#pragma unroll
      for (int r = 0; r < 4; ++r)
        kp[(wd + dt * 16 + lg * 4 + r) * CDIM + wm + mt * 16 + l15] = (bf16)acc[dt][mt][r];
}

// ---------------------------------------------------------------------------
// k_finish: ktvaug[h][144][128] bf16: rows 0..127 = sum of ktv partials,
//           row 128 = ksum, rows 129..143 = 0.  grid 576 x 256
// ---------------------------------------------------------------------------
__global__ void __launch_bounds__(256) k_finish(
    const bf16* __restrict__ ktv_part, const float* __restrict__ ksum_part,
    bf16* __restrict__ ktvaug)
{
  const int t = blockIdx.x * 256 + threadIdx.x;   // < 8*144*128
  const int h = t / (144 * 128);
  const int rem = t - h * 144 * 128;
  const int d = rem >> 7, m = rem & 127;
  float a = 0.f;
  if (d < 128) {
    for (int c = 0; c < NCHUNK; ++c) a += (float)ktv_part[(c * NH + h) * 16384 + (d << 7) + m];
  } else if (d == 128) {
    for (int c = 0; c < NCHUNK; ++c) a += ksum_part[(c * NH + h) * CDIM + m];
  }
  ktvaug[t] = (bf16)a;
}

// ---------------------------------------------------------------------------
// k_out: per 32-row tile. Per head: qs GEMM -> x2 -> (dbuf LDS) ->
//        num GEMM vs ktvaug (aug row 128 = ksum gives denominator T),
//        accO += num/T.  Then one fused vss GEMM (W2s/b2s), mean, time coord.
// grid 1024 x 256, 1 barrier per head.
// ---------------------------------------------------------------------------
__global__ void __launch_bounds__(256, 4) k_out(
    const float* __restrict__ query, const float* __restrict__ src,
    const bf16* __restrict__ wq, const float* __restrict__ Wq_b,
    const bf16* __restrict__ ktvaug,
    const bf16* __restrict__ w2s, const float* __restrict__ b2s,
    float* __restrict__ out)
{
  const int nb = blockIdx.x * QT;
  const int tid = threadIdx.x;
  const int w = tid >> 6, l = tid & 63;
  const int l15 = l & 15, lg = l >> 4;
  const int os = w * 32;

  __shared__ bf16 s_q[QT * 128];      // XOR-swizzled
  __shared__ bf16 s_s[QT * 128];
  __shared__ bf16 s_phi[2][QT * 128]; // double-buffered x2 tile
  __shared__ float s_time[4][QT] __attribute__((aligned(16)));

  const f32x4 z4 = {0.f, 0.f, 0.f, 0.f};

  // stage query + source (f32 -> bf16, swizzled)
#pragma unroll
  for (int j = 0; j < 4; ++j) {
    const int flat = tid + j * 256;
    const int n = flat >> 5, c4 = (flat & 31) * 4;
    f32x4 vq = *(const f32x4*)(query + (nb + n) * CDIM + c4);
    f32x4 vs = *(const f32x4*)(src + (nb + n) * CDIM + c4);
    bf16x4v bq, bs;
    bq[0] = (bf16)vq[0]; bq[1] = (bf16)vq[1]; bq[2] = (bf16)vq[2]; bq[3] = (bf16)vq[3];
    bs[0] = (bf16)vs[0]; bs[1] = (bf16)vs[1]; bs[2] = (bf16)vs[2]; bs[3] = (bf16)vs[3];
    *(bf16x4v*)&s_q[sidx(n, c4)] = bq;
    *(bf16x4v*)&s_s[sidx(n, c4)] = bs;
  }

  f32x4 accO[2][2];
#pragma unroll
  for (int nt = 0; nt < 2; ++nt)
#pragma unroll
    for (int ot = 0; ot < 2; ++ot) accO[nt][ot] = z4;

  __syncthreads();

  for (int h = 0; h < NH; ++h) {
    // qs GEMM
    f32x4 accQ[2][2];
#pragma unroll
    for (int nt = 0; nt < 2; ++nt)
#pragma unroll
      for (int ot = 0; ot < 2; ++ot) accQ[nt][ot] = z4;
#pragma unroll
    for (int kk = 0; kk < 4; ++kk) {
      bf16x8v a[2];
#pragma unroll
      for (int nt = 0; nt < 2; ++nt)
        a[nt] = *(const bf16x8v*)&s_q[sidx(nt * 16 + l15, kk * 32 + lg * 8)];
#pragma unroll
      for (int ot = 0; ot < 2; ++ot) {
        bf16x8v bw = *(const bf16x8v*)(wq + (h * CDIM + os + ot * 16 + l15) * CDIM + kk * 32 + lg * 8);
#pragma unroll
        for (int nt = 0; nt < 2; ++nt)
          accQ[nt][ot] = mfma16(a[nt], bw, accQ[nt][ot]);
      }
    }
    float bQ[2];
#pragma unroll
    for (int ot = 0; ot < 2; ++ot) bQ[ot] = Wq_b[h * CDIM + os + ot * 16 + l15];

    // x2 (raw, scale-free — per-row scale cancels in num/den ratio) -> s_phi[h&1]
    bf16* ph = s_phi[h & 1];
#pragma unroll
    for (int nt = 0; nt < 2; ++nt)
#pragma unroll
      for (int ot = 0; ot < 2; ++ot)
#pragma unroll
        for (int r = 0; r < 4; ++r) {
          float x = fmaxf(accQ[nt][ot][r] + bQ[ot], 0.f) + 1e-6f;
          const int row = nt * 16 + lg * 4 + r;
          ph[sidx(row, os + ot * 16 + l15)] = (bf16)(x * x);
        }
    __syncthreads();  // B1 (only barrier in the head loop)

    // numerator GEMM + denominator via aug row
    const bf16* kb = ktvaug + h * (144 * 128);
    f32x4 accN[2][2], accT[2];
#pragma unroll
    for (int nt = 0; nt < 2; ++nt) {
      accT[nt] = z4;
#pragma unroll
      for (int dt = 0; dt < 2; ++dt) accN[nt][dt] = z4;
    }
#pragma unroll
    for (int kk = 0; kk < 4; ++kk) {
      bf16x8v a[2];
#pragma unroll
      for (int nt = 0; nt < 2; ++nt)
        a[nt] = *(const bf16x8v*)&ph[sidx(nt * 16 + l15, kk * 32 + lg * 8)];
#pragma unroll
      for (int dt = 0; dt < 2; ++dt) {
        bf16x8v bk = *(const bf16x8v*)(kb + (os + dt * 16 + l15) * CDIM + kk * 32 + lg * 8);
#pragma unroll
        for (int nt = 0; nt < 2; ++nt)
          accN[nt][dt] = mfma16(a[nt], bk, accN[nt][dt]);
      }
      bf16x8v bt = *(const bf16x8v*)(kb + (128 + l15) * CDIM + kk * 32 + lg * 8);
#pragma unroll
      for (int nt = 0; nt < 2; ++nt)
        accT[nt] = mfma16(a[nt], bt, accT[nt]);
    }
    // accO += accN / T   (T broadcast from l15==0 lane of each 16-group)
#pragma unroll
    for (int nt = 0; nt < 2; ++nt)
#pragma unroll
      for (int r = 0; r < 4; ++r) {
        float tr = __shfl(accT[nt][r], l & 48);
        float m = 1.0f / tr;
#pragma unroll
        for (int dt = 0; dt < 2; ++dt)
          accO[nt][dt][r] = fmaf(accN[nt][dt][r], m, accO[nt][dt][r]);
      }
  }

  // fused vss GEMM (accumulates straight into accO)
#pragma unroll
  for (int kk = 0; kk < 4; ++kk) {
    bf16x8v a[2];
#pragma unroll
    for (int nt = 0; nt < 2; ++nt)
      a[nt] = *(const bf16x8v*)&s_s[sidx(nt * 16 + l15, kk * 32 + lg * 8)];
#pragma unroll
    for (int ot = 0; ot < 2; ++ot) {
      bf16x8v bw = *(const bf16x8v*)(w2s + (os + ot * 16 + l15) * CDIM + kk * 32 + lg * 8);
#pragma unroll
      for (int nt = 0; nt < 2; ++nt)
        accO[nt][ot] = mfma16(a[nt], bw, accO[nt][ot]);
    }
  }
  float bb[2];
#pragma unroll
  for (int ot = 0; ot < 2; ++ot) bb[ot] = b2s[os + ot * 16 + l15];

  // mean + time coordinate
  float ps[2][4];
#pragma unroll
  for (int nt = 0; nt < 2; ++nt)
#pragma unroll
    for (int r = 0; r < 4; ++r) ps[nt][r] = 0.f;
#pragma unroll
  for (int nt = 0; nt < 2; ++nt)
#pragma unroll
    for (int ot = 0; ot < 2; ++ot)
#pragma unroll
      for (int r = 0; r < 4; ++r) {
        float v = (accO[nt][ot][r] + bb[ot]) * 0.125f;
        accO[nt][ot][r] = v;
        ps[nt][r] += v * v;
      }
#pragma unroll
  for (int nt = 0; nt < 2; ++nt)
#pragma unroll
    for (int r = 0; r < 4; ++r) {
      float t = xred16(ps[nt][r]);
      if (l15 == 0) s_time[w][nt * 16 + lg * 4 + r] = t;
    }
#pragma unroll
  for (int nt = 0; nt < 2; ++nt)
#pragma unroll
    for (int ot = 0; ot < 2; ++ot)
#pragma unroll
      for (int r = 0; r < 4; ++r)
        out[(nb + nt * 16 + lg * 4 + r) * 129 + 1 + os + ot * 16 + l15] = accO[nt][ot][r];
  __syncthreads();
  if (tid < QT) {
    float S = 1.0f + s_time[0][tid] + s_time[1][tid] + s_time[2][tid] + s_time[3][tid];
    out[(nb + tid) * 129] = sqrtf(S);
  }
}

// ---------------------------------------------------------------------------
extern "C" void kernel_launch(void* const* d_in, const int* in_sizes, int n_in,
                              void* d_out, int out_size, void* d_ws, size_t ws_size,
                              hipStream_t stream) {
  const float* query  = (const float*)d_in[0];
  const float* source = (const float*)d_in[1];
  const float* Wq_w   = (const float*)d_in[2];
  const float* Wq_b   = (const float*)d_in[3];
  const float* Wk_w   = (const float*)d_in[4];
  const float* Wk_b   = (const float*)d_in[5];
  const float* Wv_w   = (const float*)d_in[6];
  const float* Wv_b   = (const float*)d_in[7];
  const float* vmw    = (const float*)d_in[8];
  const float* vmb    = (const float*)d_in[9];
  const float* ns     = (const float*)d_in[10];

  char* ws = (char*)d_ws;
  bf16*  wq        = (bf16*)(ws + 0);          // 262144
  bf16*  wk        = (bf16*)(ws + 262144);     // 262144
  bf16*  wv        = (bf16*)(ws + 524288);     // 262144
  bf16*  w2s       = (bf16*)(ws + 786432);     // 32768
  float* b2s       = (float*)(ws + 819200);    // 512
  float* Wvs       = (float*)(ws + 819712);    // 65536
  float* Wvbs      = (float*)(ws + 885248);    // 512
  bf16*  ktvaug    = (bf16*)(ws + 885760);     // 294912 (8*144*128*2)
  float* ksum_part = (float*)(ws + 1180672);   // 262144
  bf16*  ktv_part  = (bf16*)(ws + 1442816);    // 64*8*16384*2 = 16.78 MB

  k_prep<<<1024, 128, 0, stream>>>(Wq_w, Wk_w, Wv_w, Wv_b, wq, wk, wv, Wvs, Wvbs);
  k_prep2<<<128, 128, 0, stream>>>(vmw, vmb, Wvs, Wvbs, w2s, b2s);
  k_ktv<<<NCHUNK * NH, 256, 0, stream>>>(source, wk, wv, Wk_b, Wv_b, ns, ktv_part, ksum_part);
  k_finish<<<576, 256, 0, stream>>>(ktv_part, ksum_part, ktvaug);
  k_out<<<NTOK / QT, 256, 0, stream>>>(query, source, wq, Wq_b, ktvaug, w2s, b2s, (float*)d_out);
}

// Round 4
// 135.524 us; speedup vs baseline: 2.4073x; 1.3157x over previous
//
#include <hip/hip_runtime.h>

// Problem constants
#define NTOK   32768
#define CDIM   128
#define NH     8
#define QT     32     // rows per k_out block
#define NCHUNK 64     // split-K chunks for ktv
#define NSUB   8      // 64-row subtiles per chunk (NCHUNK*NSUB*64 == NTOK)

typedef __bf16 bf16;
typedef __bf16 bf16x4v __attribute__((ext_vector_type(4)));
typedef __bf16 bf16x8v __attribute__((ext_vector_type(8)));
typedef float  f32x4   __attribute__((ext_vector_type(4)));

__device__ __forceinline__ f32x4 mfma16(bf16x8v a, bf16x8v b, f32x4 c) {
  return __builtin_amdgcn_mfma_f32_16x16x32_bf16(a, b, c, 0, 0, 0);
}

__device__ __forceinline__ float xred16(float v) {
  v += __shfl_xor(v, 1);
  v += __shfl_xor(v, 2);
  v += __shfl_xor(v, 4);
  v += __shfl_xor(v, 8);
  return v;
}

// swizzled element index for row-major [R][128] bf16 LDS tiles:
// byte ^= ((row&7)<<4)  ==  elem ^= ((row&7)<<3)
__device__ __forceinline__ int sidx(int row, int col) {
  return row * 128 + (col ^ ((row & 7) << 3));
}

// Fragment-tiled global layout for MFMA B/A-side operands:
//   T[h][tile][kk][lane][8]  with  tile = col16-block, lane = (row&15) + 16*lg,
//   element j -> original [16*tile + (lane&15)][32*kk + 8*(lane>>4) + j].
// A wave's fragment load is then ONE contiguous 1KB global_load_dwordx4
// (vs 16 scattered cache lines for the row-major layout).
__device__ __forceinline__ int tidx(int h, int tile, int kk, int lane) {
  return (((h * 8 + tile) * 4 + kk) * 64 + lane) * 8;
}

// ---------------------------------------------------------------------------
// k_prep: Wq/Wk/Wv -> bf16 fragment-tiled; Wvs = sum_h Wv (f32); Wvbs = sum_h Wv_b
// grid 1024 (h,o) x 128 threads (i)
// ---------------------------------------------------------------------------
__global__ void __launch_bounds__(128) k_prep(
    const float* __restrict__ Wq, const float* __restrict__ Wk,
    const float* __restrict__ Wv, const float* __restrict__ Wv_b,
    bf16* __restrict__ wqT, bf16* __restrict__ wkT, bf16* __restrict__ wvT,
    float* __restrict__ Wvs, float* __restrict__ Wvbs)
{
  const int h = blockIdx.x >> 7, o = blockIdx.x & 127;
  const int i = threadIdx.x;
  const int src = (h * CDIM + o) * CDIM + i;
  const int ot = o >> 4, l15 = o & 15;
  const int kk = i >> 5, lg = (i >> 3) & 3, j = i & 7;
  const int dst = tidx(h, ot, kk, l15 + 16 * lg) + j;
  wqT[dst] = (bf16)Wq[src];
  wkT[dst] = (bf16)Wk[src];
  wvT[dst] = (bf16)Wv[src];
  if (h == 0) {
    float s = 0.f;
#pragma unroll
    for (int hh = 0; hh < NH; ++hh) s += Wv[(hh * CDIM + o) * CDIM + i];
    Wvs[o * CDIM + i] = s;
    if (o == 0) {
      float sb = 0.f;
#pragma unroll
      for (int hh = 0; hh < NH; ++hh) sb += Wv_b[hh * CDIM + i];
      Wvbs[i] = sb;
    }
  }
}

// ---------------------------------------------------------------------------
// k_prep2: w2sT (fragment-tiled, h-free) = vmw @ Wvs; b2s[o] = vmw[o].Wvbs + 8*vmb[o]
// ---------------------------------------------------------------------------
__global__ void __launch_bounds__(128) k_prep2(
    const float* __restrict__ vmw, const float* __restrict__ vmb,
    const float* __restrict__ Wvs, const float* __restrict__ Wvbs,
    bf16* __restrict__ w2sT, float* __restrict__ b2s)
{
  const int o = blockIdx.x, i = threadIdx.x;
  __shared__ float s_vm[128];
  __shared__ float s_rd[128];
  s_vm[i] = vmw[o * CDIM + i];
  __syncthreads();
  float acc = 0.f;
  for (int d = 0; d < CDIM; ++d) acc = fmaf(s_vm[d], Wvs[d * CDIM + i], acc);
  const int ot = o >> 4, l15 = o & 15;
  const int kk = i >> 5, lg = (i >> 3) & 3, j = i & 7;
  w2sT[tidx(0, ot, kk, l15 + 16 * lg) + j] = (bf16)acc;
  s_rd[i] = s_vm[i] * Wvbs[i];
  __syncthreads();
  for (int st = 64; st > 0; st >>= 1) {
    if (i < st) s_rd[i] += s_rd[i + st];
    __syncthreads();
  }
  if (i == 0) b2s[o] = s_rd[0] + 8.f * vmb[o];
}

// ---------------------------------------------------------------------------
// k_ktv: per (chunk c, head h): ks/v GEMMs, phi(ks), partial ktv + ksum.
// grid NCHUNK*8 = 512, 256 threads. LDS 53KB -> 2 blocks/CU; (256,2) -> no spill.
// ---------------------------------------------------------------------------
__global__ void __launch_bounds__(256, 2) k_ktv(
    const float* __restrict__ src,
    const bf16* __restrict__ wkT, const bf16* __restrict__ wvT,
    const float* __restrict__ Wk_b, const float* __restrict__ Wv_b,
    const float* __restrict__ nscale,
    bf16* __restrict__ ktv_part, float* __restrict__ ksum_part)
{
  const int bid = blockIdx.x;
  const int h = bid & 7, c = bid >> 3;
  const int tid = threadIdx.x;
  const int w = tid >> 6, l = tid & 63;
  const int l15 = l & 15, lg = l >> 4;
  const int os = w * 32, owt = os >> 4;

  __shared__ bf16 s_src[64 * 128];         // XOR-swizzled [n][i]
  __shared__ bf16 s_phiT[128][68];         // [m][n] (+pad)
  __shared__ bf16 s_vT[128][68];           // [d][n]
  __shared__ float s_red[4][64][2] __attribute__((aligned(16)));
  __shared__ float s_scale[64] __attribute__((aligned(16)));

  const float inv_ds = 1.f / (fabsf(nscale[0]) + 1e-6f);
  const f32x4 z4 = {0.f, 0.f, 0.f, 0.f};

  // hoisted loop-invariant weight fragments (coalesced tiled loads) + biases
  bf16x8v bWk[2][4], bWv[2][4];
  float bK[2], bV[2];
#pragma unroll
  for (int ot = 0; ot < 2; ++ot) {
#pragma unroll
    for (int kk = 0; kk < 4; ++kk) {
      bWk[ot][kk] = *(const bf16x8v*)(wkT + tidx(h, owt + ot, kk, l));
      bWv[ot][kk] = *(const bf16x8v*)(wvT + tidx(h, owt + ot, kk, l));
    }
    bK[ot] = Wk_b[h * CDIM + os + ot * 16 + l15];
    bV[ot] = Wv_b[h * CDIM + os + ot * 16 + l15];
  }

  const int wd = (w >> 1) * 64, wm = (w & 1) * 64;
  f32x4 acc[4][4];
#pragma unroll
  for (int dt = 0; dt < 4; ++dt)
#pragma unroll
    for (int mt = 0; mt < 4; ++mt) acc[dt][mt] = z4;
  float ksacc[2] = {0.f, 0.f};

  const int base_row = c * (NSUB * 64);

  // prologue: stage subtile 0
#pragma unroll
  for (int j = 0; j < 8; ++j) {
    const int flat = tid + j * 256;
    const int n = flat >> 5, c4 = (flat & 31) * 4;
    f32x4 v = *(const f32x4*)(src + (base_row + n) * CDIM + c4);
    bf16x4v bv;
    bv[0] = (bf16)v[0]; bv[1] = (bf16)v[1]; bv[2] = (bf16)v[2]; bv[3] = (bf16)v[3];
    *(bf16x4v*)&s_src[sidx(n, c4)] = bv;
  }
  __syncthreads();

#pragma unroll 1
  for (int s = 0; s < NSUB; ++s) {
    // ks/v GEMMs (M=n, N=o strip, K=i)
    f32x4 accK[4][2], accV[4][2];
#pragma unroll
    for (int nt = 0; nt < 4; ++nt)
#pragma unroll
      for (int ot = 0; ot < 2; ++ot) { accK[nt][ot] = z4; accV[nt][ot] = z4; }
#pragma unroll
    for (int kk = 0; kk < 4; ++kk) {
      bf16x8v a[4];
#pragma unroll
      for (int nt = 0; nt < 4; ++nt)
        a[nt] = *(const bf16x8v*)&s_src[sidx(nt * 16 + l15, kk * 32 + lg * 8)];
#pragma unroll
      for (int nt = 0; nt < 4; ++nt)
#pragma unroll
        for (int ot = 0; ot < 2; ++ot) {
          accK[nt][ot] = mfma16(a[nt], bWk[ot][kk], accK[nt][ot]);
          accV[nt][ot] = mfma16(a[nt], bWv[ot][kk], accV[nt][ot]);
        }
    }
    // x^2 + strip norms
#pragma unroll
    for (int nt = 0; nt < 4; ++nt)
#pragma unroll
      for (int r = 0; r < 4; ++r) {
        float a2 = 0.f, a4 = 0.f;
#pragma unroll
        for (int ot = 0; ot < 2; ++ot) {
          float x = (fmaxf(accK[nt][ot][r] + bK[ot], 0.f) + 1e-6f) * inv_ds;
          float x2 = x * x;
          accK[nt][ot][r] = x2;
          a2 += x2;
          a4 += x2 * x2;
        }
        a2 = xred16(a2);
        a4 = xred16(a4);
        if (l15 == 0) {
          s_red[w][nt * 16 + lg * 4 + r][0] = a2;
          s_red[w][nt * 16 + lg * 4 + r][1] = a4;
        }
      }
    __syncthreads();  // B1
    if (tid < 64) {
      float S2 = s_red[0][tid][0] + s_red[1][tid][0] + s_red[2][tid][0] + s_red[3][tid][0];
      float S4 = s_red[0][tid][1] + s_red[1][tid][1] + s_red[2][tid][1] + s_red[3][tid][1];
      s_scale[tid] = sqrtf(S2) / (sqrtf(S4) + 1e-8f);
    }
    __syncthreads();  // B2
    // transposed writes: phi = x2*scale -> s_phiT[m][n], v+bias -> s_vT[d][n]
#pragma unroll
    for (int nt = 0; nt < 4; ++nt) {
      f32x4 sc = *(const f32x4*)&s_scale[nt * 16 + lg * 4];
#pragma unroll
      for (int ot = 0; ot < 2; ++ot) {
        bf16x4v ph, vv;
#pragma unroll
        for (int r = 0; r < 4; ++r) {
          float p = accK[nt][ot][r] * sc[r];
          ksacc[ot] += p;
          ph[r] = (bf16)p;
          vv[r] = (bf16)(accV[nt][ot][r] + bV[ot]);
        }
        const int colb = os + ot * 16 + l15;
        *(bf16x4v*)&s_phiT[colb][nt * 16 + lg * 4] = ph;
        *(bf16x4v*)&s_vT[colb][nt * 16 + lg * 4] = vv;
      }
    }
    __syncthreads();  // B3
    // stage next subtile (issues global loads; overlaps the ktv MFMA below)
    if (s + 1 < NSUB) {
      const int nb = base_row + (s + 1) * 64;
#pragma unroll
      for (int j = 0; j < 8; ++j) {
        const int flat = tid + j * 256;
        const int n = flat >> 5, c4 = (flat & 31) * 4;
        f32x4 v = *(const f32x4*)(src + (nb + n) * CDIM + c4);
        bf16x4v bv;
        bv[0] = (bf16)v[0]; bv[1] = (bf16)v[1]; bv[2] = (bf16)v[2]; bv[3] = (bf16)v[3];
        *(bf16x4v*)&s_src[sidx(n, c4)] = bv;
      }
    }
    // ktv += v^T phi
#pragma unroll
    for (int kk = 0; kk < 2; ++kk) {
      bf16x8v aV[4], bP[4];
#pragma unroll
      for (int dt = 0; dt < 4; ++dt)
        aV[dt] = *(const bf16x8v*)&s_vT[wd + dt * 16 + l15][kk * 32 + lg * 8];
#pragma unroll
      for (int mt = 0; mt < 4; ++mt)
        bP[mt] = *(const bf16x8v*)&s_phiT[wm + mt * 16 + l15][kk * 32 + lg * 8];
#pragma unroll
      for (int dt = 0; dt < 4; ++dt)
#pragma unroll
        for (int mt = 0; mt < 4; ++mt)
          acc[dt][mt] = mfma16(aV[dt], bP[mt], acc[dt][mt]);
    }
    if (s + 1 < NSUB) __syncthreads();  // B4: stage complete
  }

  // ksum partial
#pragma unroll
  for (int ot = 0; ot < 2; ++ot) {
    ksacc[ot] += __shfl_xor(ksacc[ot], 16);
    ksacc[ot] += __shfl_xor(ksacc[ot], 32);
  }
  if (l < 16) {
#pragma unroll
    for (int ot = 0; ot < 2; ++ot)
      ksum_part[(c * NH + h) * CDIM + os + ot * 16 + l] = ksacc[ot];
  }
  // ktv partial store [c][h][d][m]
  bf16* kp = ktv_part + (c * NH + h) * CDIM * CDIM;
#pragma unroll
  for (int dt = 0; dt < 4; ++dt)
#pragma unroll
    for (int mt = 0; mt < 4; ++mt)
#pragma unroll
      for (int r = 0; r < 4; ++r)
        kp[(wd + dt * 16 + lg * 4 + r) * CDIM + wm + mt * 16 + l15] = (bf16)acc[dt][mt][r];
}

// ---------------------------------------------------------------------------
// k_finish: reduce split-K partials into fragment-tiled ktvT[h][dt][kk][lane][8]
//           and ksb[h][kk][lane][8] (B-frag of [ksum; 0...] -> T in col 0).
// grid 576 x 256
// ---------------------------------------------------------------------------
__global__ void __launch_bounds__(256) k_finish(
    const bf16* __restrict__ ktv_part, const float* __restrict__ ksum_part,
    bf16* __restrict__ ktvT, bf16* __restrict__ ksb)
{
  const int b = blockIdx.x;
  if (b < 512) {
    const int t = b * 256 + threadIdx.x;          // < 131072 = 8*128*128
    const int h = t >> 14;
    const int rem = t & 16383;
    const int d = rem >> 7, m = rem & 127;
    float a = 0.f;
    for (int c = 0; c < NCHUNK; ++c)
      a += (float)ktv_part[(c * NH + h) * 16384 + (d << 7) + m];
    const int dt = d >> 4, l15 = d & 15;
    const int kk = m >> 5, lg = (m >> 3) & 3, j = m & 7;
    ktvT[tidx(h, dt, kk, l15 + 16 * lg) + j] = (bf16)a;
  } else {
    const int t = (b - 512) * 256 + threadIdx.x;  // < 16384 = 8*4*64*8
    const int h = t >> 11;
    const int rem = t & 2047;
    const int kk = rem >> 9, lane = (rem >> 3) & 63, j = rem & 7;
    const int l15 = lane & 15, lg = lane >> 4;
    float a = 0.f;
    if (l15 == 0) {
      const int m = 32 * kk + 8 * lg + j;
      for (int c = 0; c < NCHUNK; ++c) a += ksum_part[(c * NH + h) * CDIM + m];
    }
    ksb[t] = (bf16)a;
  }
}

// ---------------------------------------------------------------------------
// k_out: per 32-row tile. Per head: prefetch tiled frags -> qs GEMM ->
//        x2 -> dbuf LDS -> num GEMM (+T via ksb col-0 trick) -> accO += num/T.
//        Then fused vss GEMM, mean, time coord.  1 barrier per head.
// ---------------------------------------------------------------------------
__global__ void __launch_bounds__(256, 2) k_out(
    const float* __restrict__ query, const float* __restrict__ src,
    const bf16* __restrict__ wqT, const float* __restrict__ Wq_b,
    const bf16* __restrict__ ktvT, const bf16* __restrict__ ksb,
    const bf16* __restrict__ w2sT, const float* __restrict__ b2s,
    float* __restrict__ out)
{
  const int nb = blockIdx.x * QT;
  const int tid = threadIdx.x;
  const int w = tid >> 6, l = tid & 63;
  const int l15 = l & 15, lg = l >> 4;
  const int os = w * 32, owt = os >> 4;

  __shared__ bf16 s_q[QT * 128];      // XOR-swizzled
  __shared__ bf16 s_s[QT * 128];
  __shared__ bf16 s_phi[2][QT * 128]; // double-buffered x2 tile
  __shared__ float s_time[4][QT] __attribute__((aligned(16)));

  const f32x4 z4 = {0.f, 0.f, 0.f, 0.f};

  // stage query + source (f32 -> bf16, swizzled)
#pragma unroll
  for (int j = 0; j < 4; ++j) {
    const int flat = tid + j * 256;
    const int n = flat >> 5, c4 = (flat & 31) * 4;
    f32x4 vq = *(const f32x4*)(query + (nb + n) * CDIM + c4);
    f32x4 vs = *(const f32x4*)(src + (nb + n) * CDIM + c4);
    bf16x4v bq, bs;
    bq[0] = (bf16)vq[0]; bq[1] = (bf16)vq[1]; bq[2] = (bf16)vq[2]; bq[3] = (bf16)vq[3];
    bs[0] = (bf16)vs[0]; bs[1] = (bf16)vs[1]; bs[2] = (bf16)vs[2]; bs[3] = (bf16)vs[3];
    *(bf16x4v*)&s_q[sidx(n, c4)] = bq;
    *(bf16x4v*)&s_s[sidx(n, c4)] = bs;
  }

  f32x4 accO[2][2];
#pragma unroll
  for (int nt = 0; nt < 2; ++nt)
#pragma unroll
    for (int ot = 0; ot < 2; ++ot) accO[nt][ot] = z4;

  __syncthreads();

  // hoist q A-frags (s_q read-only for the rest of the kernel)
  bf16x8v aq[2][4];
#pragma unroll
  for (int nt = 0; nt < 2; ++nt)
#pragma unroll
    for (int kk = 0; kk < 4; ++kk)
      aq[nt][kk] = *(const bf16x8v*)&s_q[sidx(nt * 16 + l15, kk * 32 + lg * 8)];

  for (int h = 0; h < NH; ++h) {
    // prefetch all tiled fragments for this head (coalesced 1KB loads);
    // latency hides under qs GEMM + barrier
    bf16x8v wf[2][4], kf[2][4], kt[4];
#pragma unroll
    for (int ot = 0; ot < 2; ++ot)
#pragma unroll
      for (int kk = 0; kk < 4; ++kk) {
        wf[ot][kk] = *(const bf16x8v*)(wqT + tidx(h, owt + ot, kk, l));
        kf[ot][kk] = *(const bf16x8v*)(ktvT + tidx(h, owt + ot, kk, l));
      }
#pragma unroll
    for (int kk = 0; kk < 4; ++kk)
      kt[kk] = *(const bf16x8v*)(ksb + ((h * 4 + kk) * 64 + l) * 8);
    float bQ[2];
#pragma unroll
    for (int ot = 0; ot < 2; ++ot) bQ[ot] = Wq_b[h * CDIM + os + ot * 16 + l15];

    // qs GEMM (A = hoisted q frags, B = prefetched wq frags)
    f32x4 accQ[2][2];
#pragma unroll
    for (int nt = 0; nt < 2; ++nt)
#pragma unroll
      for (int ot = 0; ot < 2; ++ot) accQ[nt][ot] = z4;
#pragma unroll
    for (int kk = 0; kk < 4; ++kk)
#pragma unroll
      for (int ot = 0; ot < 2; ++ot)
#pragma unroll
        for (int nt = 0; nt < 2; ++nt)
          accQ[nt][ot] = mfma16(aq[nt][kk], wf[ot][kk], accQ[nt][ot]);

    // x2 (scale-free; per-row phi scale cancels in num/den) -> s_phi[h&1]
    bf16* ph = s_phi[h & 1];
#pragma unroll
    for (int nt = 0; nt < 2; ++nt)
#pragma unroll
      for (int ot = 0; ot < 2; ++ot)
#pragma unroll
        for (int r = 0; r < 4; ++r) {
          float x = fmaxf(accQ[nt][ot][r] + bQ[ot], 0.f) + 1e-6f;
          ph[sidx(nt * 16 + lg * 4 + r, os + ot * 16 + l15)] = (bf16)(x * x);
        }
    __syncthreads();  // B1 (only barrier in the head loop)

    // phi A-frags
    bf16x8v ap[2][4];
#pragma unroll
    for (int nt = 0; nt < 2; ++nt)
#pragma unroll
      for (int kk = 0; kk < 4; ++kk)
        ap[nt][kk] = *(const bf16x8v*)&ph[sidx(nt * 16 + l15, kk * 32 + lg * 8)];

    // numerator GEMM + denominator (ksb col-0 trick)
    f32x4 accN[2][2], accT[2];
#pragma unroll
    for (int nt = 0; nt < 2; ++nt) {
      accT[nt] = z4;
#pragma unroll
      for (int dt = 0; dt < 2; ++dt) accN[nt][dt] = z4;
    }
#pragma unroll
    for (int kk = 0; kk < 4; ++kk) {
#pragma unroll
      for (int dt = 0; dt < 2; ++dt)
#pragma unroll
        for (int nt = 0; nt < 2; ++nt)
          accN[nt][dt] = mfma16(ap[nt][kk], kf[dt][kk], accN[nt][dt]);
#pragma unroll
      for (int nt = 0; nt < 2; ++nt)
        accT[nt] = mfma16(ap[nt][kk], kt[kk], accT[nt]);
    }
    // accO += accN / T  (T lives in col 0 = lane l&48 of each 16-group)
#pragma unroll
    for (int nt = 0; nt < 2; ++nt)
#pragma unroll
      for (int r = 0; r < 4; ++r) {
        float tr = __shfl(accT[nt][r], l & 48);
        float m = 1.0f / tr;
#pragma unroll
        for (int dt = 0; dt < 2; ++dt)
          accO[nt][dt][r] = fmaf(accN[nt][dt][r], m, accO[nt][dt][r]);
      }
  }

  // fused vss GEMM (accumulates straight into accO)
#pragma unroll
  for (int kk = 0; kk < 4; ++kk) {
    bf16x8v a[2];
#pragma unroll
    for (int nt = 0; nt < 2; ++nt)
      a[nt] = *(const bf16x8v*)&s_s[sidx(nt * 16 + l15, kk * 32 + lg * 8)];
#pragma unroll
    for (int ot = 0; ot < 2; ++ot) {
      bf16x8v bw = *(const bf16x8v*)(w2sT + tidx(0, owt + ot, kk, l));
#pragma unroll
      for (int nt = 0; nt < 2; ++nt)
        accO[nt][ot] = mfma16(a[nt], bw, accO[nt][ot]);
    }
  }
  float bb[2];
#pragma unroll
  for (int ot = 0; ot < 2; ++ot) bb[ot] = b2s[os + ot * 16 + l15];

  // mean + time coordinate
  float ps[2][4];
#pragma unroll
  for (int nt = 0; nt < 2; ++nt)
#pragma unroll
    for (int r = 0; r < 4; ++r) ps[nt][r] = 0.f;
#pragma unroll
  for (int nt = 0; nt < 2; ++nt)
#pragma unroll
    for (int ot = 0; ot < 2; ++ot)
#pragma unroll
      for (int r = 0; r < 4; ++r) {
        float v = (accO[nt][ot][r] + bb[ot]) * 0.125f;
        accO[nt][ot][r] = v;
        ps[nt][r] += v * v;
      }
#pragma unroll
  for (int nt = 0; nt < 2; ++nt)
#pragma unroll
    for (int r = 0; r < 4; ++r) {
      float t = xred16(ps[nt][r]);
      if (l15 == 0) s_time[w][nt * 16 + lg * 4 + r] = t;
    }
#pragma unroll
  for (int nt = 0; nt < 2; ++nt)
#pragma unroll
    for (int ot = 0; ot < 2; ++ot)
#pragma unroll
      for (int r = 0; r < 4; ++r)
        out[(nb + nt * 16 + lg * 4 + r) * 129 + 1 + os + ot * 16 + l15] = accO[nt][ot][r];
  __syncthreads();
  if (tid < QT) {
    float S = 1.0f + s_time[0][tid] + s_time[1][tid] + s_time[2][tid] + s_time[3][tid];
    out[(nb + tid) * 129] = sqrtf(S);
  }
}

// ---------------------------------------------------------------------------
extern "C" void kernel_launch(void* const* d_in, const int* in_sizes, int n_in,
                              void* d_out, int out_size, void* d_ws, size_t ws_size,
                              hipStream_t stream) {
  const float* query  = (const float*)d_in[0];
  const float* source = (const float*)d_in[1];
  const float* Wq_w   = (const float*)d_in[2];
  const float* Wq_b   = (const float*)d_in[3];
  const float* Wk_w   = (const float*)d_in[4];
  const float* Wk_b   = (const float*)d_in[5];
  const float* Wv_w   = (const float*)d_in[6];
  const float* Wv_b   = (const float*)d_in[7];
  const float* vmw    = (const float*)d_in[8];
  const float* vmb    = (const float*)d_in[9];
  const float* ns     = (const float*)d_in[10];

  char* ws = (char*)d_ws;
  bf16*  wqT       = (bf16*)(ws + 0);          // 262144
  bf16*  wkT       = (bf16*)(ws + 262144);     // 262144
  bf16*  wvT       = (bf16*)(ws + 524288);     // 262144
  bf16*  w2sT      = (bf16*)(ws + 786432);     // 32768
  float* b2s       = (float*)(ws + 819200);    // 512
  float* Wvs       = (float*)(ws + 819712);    // 65536
  float* Wvbs      = (float*)(ws + 885248);    // 512
  bf16*  ktvT      = (bf16*)(ws + 885760);     // 262144
  bf16*  ksb       = (bf16*)(ws + 1147904);    // 32768
  float* ksum_part = (float*)(ws + 1180672);   // 262144
  bf16*  ktv_part  = (bf16*)(ws + 1442816);    // 16777216

  k_prep<<<1024, 128, 0, stream>>>(Wq_w, Wk_w, Wv_w, Wv_b, wqT, wkT, wvT, Wvs, Wvbs);
  k_prep2<<<128, 128, 0, stream>>>(vmw, vmb, Wvs, Wvbs, w2sT, b2s);
  k_ktv<<<NCHUNK * NH, 256, 0, stream>>>(source, wkT, wvT, Wk_b, Wv_b, ns, ktv_part, ksum_part);
  k_finish<<<576, 256, 0, stream>>>(ktv_part, ksum_part, ktvT, ksb);
  k_out<<<NTOK / QT, 256, 0, stream>>>(query, source, wqT, Wq_b, ktvT, ksb, w2sT, b2s, (float*)d_out);
}